// Round 2
// baseline (2359.657 us; speedup 1.0000x reference)
//
#include <hip/hip_runtime.h>

#define NN 20000
#define NE 320000
#define DIMX 256
#define NHEADS 8
#define HC 32
#define EDIMX 32
#define DFFX 1024

__device__ __forceinline__ float b2f(unsigned short u) {
  return __uint_as_float(((unsigned)u) << 16);
}
__device__ __forceinline__ unsigned short f2b(float f) {
  unsigned u = __float_as_uint(f);
  u += 0x7FFF + ((u >> 16) & 1);
  return (unsigned short)(u >> 16);
}

// ---------------- dtype detect: 1 = inputs are f32, 0 = inputs are bf16 ----------------
__global__ void k_detect(const unsigned short* __restrict__ in, int* __restrict__ flag) {
  __shared__ int cnt_s;
  if (threadIdx.x == 0) cnt_s = 0;
  __syncthreads();
  int c = 0;
  for (int i = threadIdx.x; i < 4096; i += 256) {
    int ex = (in[i] >> 7) & 0xFF;
    if (ex >= 0xC6) c++;  // |x| >= 2^71 as bf16: impossible for real activations
  }
  atomicAdd(&cnt_s, c);
  __syncthreads();
  if (threadIdx.x == 0) flag[0] = (cnt_s > 64) ? 1 : 0;
}

// ---------------- universal input -> f32 convert ----------------
__global__ void k_cvt(const void* __restrict__ in, float* __restrict__ out, int n,
                      const int* __restrict__ flag) {
  int i = blockIdx.x * 256 + threadIdx.x;
  if (i >= n) return;
  if (flag[0]) out[i] = ((const float*)in)[i];
  else out[i] = b2f(((const unsigned short*)in)[i]);
}

// ---------------- edge count + edge-attr sum ----------------
__global__ void k_edge_count(const int* __restrict__ dst, const float* __restrict__ ew,
                             int* __restrict__ cnt, float* __restrict__ easum, int E) {
  int e = blockIdx.x * 256 + threadIdx.x;
  if (e >= E) return;
  int d = dst[e];
  atomicAdd(&cnt[d], 1);
  for (int k = 0; k < EDIMX; k++)
    atomicAdd(&easum[d * EDIMX + k], ew[(size_t)e * EDIMX + k]);
}

// ---------------- single-block scan -> rowptr ----------------
__global__ void k_scan(const int* __restrict__ cnt, int* __restrict__ rowptr, int N) {
  __shared__ int sums[256];
  int t = threadIdx.x;
  int chunk = (N + 255) / 256;
  int lo = t * chunk, hi = lo + chunk;
  if (hi > N) hi = N;
  if (lo > N) lo = N;
  int s = 0;
  for (int n = lo; n < hi; n++) s += cnt[n] + 1;
  sums[t] = s;
  __syncthreads();
  for (int off = 1; off < 256; off <<= 1) {
    int v = (t >= off) ? sums[t - off] : 0;
    __syncthreads();
    sums[t] += v;
    __syncthreads();
  }
  int run = sums[t] - s;  // exclusive prefix
  for (int n = lo; n < hi; n++) { rowptr[n] = run; run += cnt[n] + 1; }
  if (t == 255) rowptr[N] = run;
}

// ---------------- loop_ea = easum / max(cnt,1) ----------------
__global__ void k_loop_ea(float* __restrict__ easum, const int* __restrict__ cnt, int N) {
  int i = blockIdx.x * 256 + threadIdx.x;
  if (i >= N * EDIMX) return;
  int c = cnt[i >> 5];
  easum[i] = easum[i] / (float)(c > 0 ? c : 1);
}

// ---------------- CSR fill (edges + self loops) ----------------
__global__ void k_fill(const int* __restrict__ dst, const int* __restrict__ rowptr,
                       int* __restrict__ fill, int* __restrict__ eidx, int N, int E) {
  int t = blockIdx.x * 256 + threadIdx.x;
  if (t < E) {
    int d = dst[t];
    int pos = rowptr[d] + atomicAdd(&fill[d], 1);
    eidx[pos] = t;
  } else if (t < E + N) {
    int n = t - E;
    eidx[rowptr[n + 1] - 1] = E + n;  // self loop id
  }
}

// ---------------- tiled GEMM: C[M,Nc] = A[M,K](f32) @ B[K,Nc](f32) ----------------
template <bool BIAS, bool RELU>
__global__ __launch_bounds__(256) void k_gemm(const float* __restrict__ A,
                                              const float* __restrict__ B,
                                              const float* __restrict__ bias,
                                              float* __restrict__ C, int M, int K, int Nc) {
  __shared__ float As[16][64];
  __shared__ float Bs[16][64];
  int tid = threadIdx.x;
  int tx = tid & 15, ty = tid >> 4;
  int m0 = blockIdx.y * 64, n0 = blockIdx.x * 64;
  int am = tid >> 2, ak = (tid & 3) * 4;
  int bk = tid >> 4, bn = (tid & 15) * 4;
  float4 acc[4];
  for (int i = 0; i < 4; i++) acc[i] = make_float4(0.f, 0.f, 0.f, 0.f);
  for (int k0 = 0; k0 < K; k0 += 16) {
    float4 av = make_float4(0.f, 0.f, 0.f, 0.f);
    if (m0 + am < M) av = *(const float4*)(A + (size_t)(m0 + am) * K + k0 + ak);
    As[ak + 0][am] = av.x; As[ak + 1][am] = av.y; As[ak + 2][am] = av.z; As[ak + 3][am] = av.w;
    *(float4*)&Bs[bk][bn] = *(const float4*)(B + (size_t)(k0 + bk) * Nc + n0 + bn);
    __syncthreads();
#pragma unroll
    for (int k = 0; k < 16; k++) {
      float4 a = *(const float4*)&As[k][ty * 4];
      float4 b = *(const float4*)&Bs[k][tx * 4];
      acc[0].x += a.x * b.x; acc[0].y += a.x * b.y; acc[0].z += a.x * b.z; acc[0].w += a.x * b.w;
      acc[1].x += a.y * b.x; acc[1].y += a.y * b.y; acc[1].z += a.y * b.z; acc[1].w += a.y * b.w;
      acc[2].x += a.z * b.x; acc[2].y += a.z * b.y; acc[2].z += a.z * b.z; acc[2].w += a.z * b.w;
      acc[3].x += a.w * b.x; acc[3].y += a.w * b.y; acc[3].z += a.w * b.z; acc[3].w += a.w * b.w;
    }
    __syncthreads();
  }
  float4 bia = make_float4(0.f, 0.f, 0.f, 0.f);
  if (BIAS) bia = *(const float4*)(bias + n0 + tx * 4);
  for (int i = 0; i < 4; i++) {
    int m = m0 + ty * 4 + i;
    if (m >= M) continue;
    float4 v = acc[i];
    if (BIAS) { v.x += bia.x; v.y += bia.y; v.z += bia.z; v.w += bia.w; }
    if (RELU) {
      v.x = fmaxf(v.x, 0.f); v.y = fmaxf(v.y, 0.f);
      v.z = fmaxf(v.z, 0.f); v.w = fmaxf(v.w, 0.f);
    }
    *(float4*)(C + (size_t)m * Nc + n0 + tx * 4) = v;
  }
}

// ---------------- per-edge attention score (1 wave = 1 edge) ----------------
__global__ __launch_bounds__(256) void k_score(const float* __restrict__ xl,
                                               const float* __restrict__ xr,
                                               const int* __restrict__ src,
                                               const int* __restrict__ dst,
                                               const float* __restrict__ ew,
                                               const float* __restrict__ loop_ea,
                                               const float* __restrict__ We,
                                               const float* __restrict__ att,
                                               float* __restrict__ score, int E, int N) {
  __shared__ float We_s[EDIMX * DIMX];  // 32 KB
  __shared__ float att_s[DIMX];         // 1 KB
  int tid = threadIdx.x;
  {
    const float4* Wg = (const float4*)We;
    float4* Ws = (float4*)We_s;
    for (int i = tid; i < EDIMX * DIMX / 4; i += 256) Ws[i] = Wg[i];
    att_s[tid] = att[tid];
  }
  __syncthreads();
  int wave = tid >> 6, lane = tid & 63;
  int eid = blockIdx.x * 4 + wave;
  if (eid >= E + N) return;
  int s, d;
  float eav = 0.f;
  if (eid < E) {
    s = src[eid]; d = dst[eid];
    if (lane < EDIMX) eav = ew[(size_t)eid * EDIMX + lane];
  } else {
    s = d = eid - E;
    if (lane < EDIMX) eav = loop_ea[(size_t)(eid - E) * EDIMX + lane];
  }
  int c0 = lane * 4;
  float ee0 = 0.f, ee1 = 0.f, ee2 = 0.f, ee3 = 0.f;
  const float4* Wrow = (const float4*)We_s;
#pragma unroll
  for (int k = 0; k < EDIMX; k++) {
    float a = __shfl(eav, k, 64);
    float4 w = Wrow[k * 64 + lane];
    ee0 += a * w.x; ee1 += a * w.y; ee2 += a * w.z; ee3 += a * w.w;
  }
  float4 vl = *(const float4*)(xl + (size_t)s * DIMX + c0);
  float4 vr = *(const float4*)(xr + (size_t)d * DIMX + c0);
  float z0 = vl.x + vr.x + ee0, z1 = vl.y + vr.y + ee1;
  float z2 = vl.z + vr.z + ee2, z3 = vl.w + vr.w + ee3;
  z0 = z0 > 0.f ? z0 : 0.2f * z0; z1 = z1 > 0.f ? z1 : 0.2f * z1;
  z2 = z2 > 0.f ? z2 : 0.2f * z2; z3 = z3 > 0.f ? z3 : 0.2f * z3;
  float4 a4 = *(const float4*)&att_s[c0];
  float p = z0 * a4.x + z1 * a4.y + z2 * a4.z + z3 * a4.w;
  p += __shfl_xor(p, 1, 64);
  p += __shfl_xor(p, 2, 64);
  p += __shfl_xor(p, 4, 64);
  if ((lane & 7) == 0) score[(size_t)eid * NHEADS + (lane >> 3)] = p;
}

// ---------------- per-node segment softmax (1 wave = 1 node) ----------------
__global__ __launch_bounds__(256) void k_softmax(const int* __restrict__ rowptr,
                                                 const int* __restrict__ eidx,
                                                 float* __restrict__ score, int N) {
  int wave = threadIdx.x >> 6, lane = threadIdx.x & 63;
  int node = blockIdx.x * 4 + wave;
  if (node >= N) return;
  int begin = rowptr[node], end = rowptr[node + 1], len = end - begin;
  int head = lane & 7, slot = lane >> 3;
  float m = -3.4e38f;
  for (int base = 0; base < len; base += 8) {
    int idx = base + slot;
    if (idx < len) {
      int eid = eidx[begin + idx];
      m = fmaxf(m, score[(size_t)eid * NHEADS + head]);
    }
  }
  m = fmaxf(m, __shfl_xor(m, 8, 64));
  m = fmaxf(m, __shfl_xor(m, 16, 64));
  m = fmaxf(m, __shfl_xor(m, 32, 64));
  float ssum = 0.f;
  for (int base = 0; base < len; base += 8) {
    int idx = base + slot;
    if (idx < len) {
      int eid = eidx[begin + idx];
      ssum += expf(score[(size_t)eid * NHEADS + head] - m);
    }
  }
  ssum += __shfl_xor(ssum, 8, 64);
  ssum += __shfl_xor(ssum, 16, 64);
  ssum += __shfl_xor(ssum, 32, 64);
  float inv = 1.f / ssum;
  for (int base = 0; base < len; base += 8) {
    int idx = base + slot;
    if (idx < len) {
      int eid = eidx[begin + idx];
      size_t p = (size_t)eid * NHEADS + head;
      score[p] = expf(score[p] - m) * inv;
    }
  }
}

// ---------------- per-node aggregation (1 wave = 1 node) ----------------
__global__ __launch_bounds__(256) void k_aggregate(const float* __restrict__ xl,
                                                   const float* __restrict__ alpha,
                                                   const int* __restrict__ rowptr,
                                                   const int* __restrict__ eidx,
                                                   const int* __restrict__ src,
                                                   const float* __restrict__ bias,
                                                   float* __restrict__ out, int N, int E) {
  int wave = threadIdx.x >> 6, lane = threadIdx.x & 63;
  int node = blockIdx.x * 4 + wave;
  if (node >= N) return;
  int begin = rowptr[node], end = rowptr[node + 1];
  int head = lane >> 3;
  const float4* xl4 = (const float4*)xl;
  float4 acc = make_float4(0.f, 0.f, 0.f, 0.f);
  for (int p = begin; p < end; p++) {
    int eid = eidx[p];
    int s = (eid < E) ? src[eid] : node;
    float a = alpha[(size_t)eid * NHEADS + head];
    float4 v = xl4[(size_t)s * 64 + lane];
    acc.x += a * v.x; acc.y += a * v.y; acc.z += a * v.z; acc.w += a * v.w;
  }
  float4 bia = *(const float4*)(bias + lane * 4);
  acc.x += bia.x; acc.y += bia.y; acc.z += bia.z; acc.w += bia.w;
  ((float4*)out)[(size_t)node * 64 + lane] = acc;
}

// ---------------- BN stats (sum, sumsq per channel) ----------------
__global__ __launch_bounds__(256) void k_bnstats(const float* __restrict__ x,
                                                 float* __restrict__ sums, int N) {
  int c = threadIdx.x;
  float s = 0.f, sq = 0.f;
  for (int n = blockIdx.x; n < N; n += gridDim.x) {
    float v = x[(size_t)n * DIMX + c];
    s += v; sq += v * v;
  }
  atomicAdd(&sums[c], s);
  atomicAdd(&sums[DIMX + c], sq);
}

// ---------------- BN + leaky_relu(0.01) + residual ----------------
template <bool FINAL>
__global__ __launch_bounds__(256) void k_bnapply(const float* __restrict__ x,
                                                 const float* __restrict__ res,
                                                 const float* __restrict__ sums,
                                                 const float* __restrict__ g,
                                                 const float* __restrict__ b,
                                                 void* __restrict__ out, int N,
                                                 const int* __restrict__ flag) {
  int i = blockIdx.x * 256 + threadIdx.x;
  if (i >= N * DIMX) return;
  int c = i & (DIMX - 1);
  float invn = 1.f / (float)N;
  float mu = sums[c] * invn;
  float var = sums[DIMX + c] * invn - mu * mu;
  float rstd = rsqrtf(var + 1e-5f);
  float y = (x[i] - mu) * rstd * g[c] + b[c];
  y = y > 0.f ? y : 0.01f * y;
  y += res[i];
  if (FINAL) {
    if (flag[0]) ((float*)out)[i] = y;
    else ((unsigned short*)out)[i] = f2b(y);
  } else {
    ((float*)out)[i] = y;
  }
}

extern "C" void kernel_launch(void* const* d_in, const int* in_sizes, int n_in,
                              void* d_out, int out_size, void* d_ws, size_t ws_size,
                              hipStream_t stream) {
  (void)in_sizes; (void)n_in; (void)out_size; (void)ws_size;
  const int* ei = (const int*)d_in[1];
  const int* srcp = ei;
  const int* dstp = ei + NE;

  char* w = (char*)d_ws;
  auto alloc = [&](size_t bytes) {
    char* p = w;
    w += (bytes + 255) & ~(size_t)255;
    return p;
  };
  float* H0 = (float*)alloc((size_t)NN * DIMX * 4);
  float* H1 = (float*)alloc((size_t)NN * DIMX * 4);
  float* G = (float*)alloc((size_t)NN * DIMX * 4);
  float* XL = (float*)alloc((size_t)NN * DIMX * 4);
  float* XR = (float*)alloc((size_t)NN * DIMX * 4);
  float* SCORE = (float*)alloc((size_t)(NE + NN) * NHEADS * 4);
  float* LEA = (float*)alloc((size_t)NN * EDIMX * 4);
  float* EWF = (float*)alloc((size_t)NE * EDIMX * 4);
  float* PAR = (float*)alloc((size_t)806656 * 4);
  int* CNT = (int*)alloc((size_t)NN * 4);
  int* ROWPTR = (int*)alloc((size_t)(NN + 1) * 4);
  int* FILL = (int*)alloc((size_t)NN * 4);
  int* EIDX = (int*)alloc((size_t)(NE + NN) * 4);
  float* BNS = (float*)alloc(2 * DIMX * 4);
  int* FLAG = (int*)alloc(256);
  float* FF1 = (float*)alloc((size_t)NN * DFFX * 4);

  // ---- dtype detect + convert everything to f32 ----
  k_detect<<<1, 256, 0, stream>>>((const unsigned short*)d_in[0], FLAG);
  k_cvt<<<(NN * DIMX + 255) / 256, 256, 0, stream>>>(d_in[0], H0, NN * DIMX, FLAG);
  k_cvt<<<(NE * EDIMX + 255) / 256, 256, 0, stream>>>(d_in[2], EWF, NE * EDIMX, FLAG);
  static const int psz[20] = {65536, 65536, 8192, 256, 256,
                              65536, 65536, 8192, 256, 256,
                              256, 256, 256, 256, 256, 256,
                              262144, 1024, 262144, 256};
  float* pp[20];
  {
    int off = 0;
    for (int i = 0; i < 20; i++) { pp[i] = PAR + off; off += psz[i]; }
    for (int i = 0; i < 20; i++)
      k_cvt<<<(psz[i] + 255) / 256, 256, 0, stream>>>(d_in[3 + i], pp[i], psz[i], FLAG);
  }
  const float* g_Wl[2] = {pp[0], pp[5]};
  const float* g_Wr[2] = {pp[1], pp[6]};
  const float* g_We[2] = {pp[2], pp[7]};
  const float* g_att[2] = {pp[3], pp[8]};
  const float* g_b[2] = {pp[4], pp[9]};
  const float* bn_g[3] = {pp[10], pp[12], pp[14]};
  const float* bn_b[3] = {pp[11], pp[13], pp[15]};
  const float* ff_W1 = pp[16];
  const float* ff_b1 = pp[17];
  const float* ff_W2 = pp[18];
  const float* ff_b2 = pp[19];

  // ---- graph structure (shared by both GAT layers) ----
  hipMemsetAsync(CNT, 0, (size_t)NN * 4, stream);
  hipMemsetAsync(FILL, 0, (size_t)NN * 4, stream);
  hipMemsetAsync(LEA, 0, (size_t)NN * EDIMX * 4, stream);
  k_edge_count<<<(NE + 255) / 256, 256, 0, stream>>>(dstp, EWF, CNT, LEA, NE);
  k_scan<<<1, 256, 0, stream>>>(CNT, ROWPTR, NN);
  k_loop_ea<<<(NN * EDIMX + 255) / 256, 256, 0, stream>>>(LEA, CNT, NN);
  k_fill<<<(NE + NN + 255) / 256, 256, 0, stream>>>(dstp, ROWPTR, FILL, EIDX, NN, NE);

  auto run_gat = [&](const float* x, int li, int bi, float* hout) {
    dim3 gg(DIMX / 64, (NN + 63) / 64);
    k_gemm<false, false><<<gg, 256, 0, stream>>>(x, g_Wl[li], nullptr, XL, NN, DIMX, DIMX);
    k_gemm<false, false><<<gg, 256, 0, stream>>>(x, g_Wr[li], nullptr, XR, NN, DIMX, DIMX);
    k_score<<<(NE + NN + 3) / 4, 256, 0, stream>>>(XL, XR, srcp, dstp, EWF, LEA, g_We[li],
                                                   g_att[li], SCORE, NE, NN);
    k_softmax<<<(NN + 3) / 4, 256, 0, stream>>>(ROWPTR, EIDX, SCORE, NN);
    k_aggregate<<<(NN + 3) / 4, 256, 0, stream>>>(XL, SCORE, ROWPTR, EIDX, srcp, g_b[li], G,
                                                  NN, NE);
    hipMemsetAsync(BNS, 0, 2 * DIMX * 4, stream);
    k_bnstats<<<128, 256, 0, stream>>>(G, BNS, NN);
    k_bnapply<false><<<(NN * DIMX + 255) / 256, 256, 0, stream>>>(G, x, BNS, bn_g[bi], bn_b[bi],
                                                                  hout, NN, FLAG);
  };

  run_gat(H0, 0, 0, H1);  // h1 = nf + lrelu(bn(gat1(nf)))
  run_gat(H1, 1, 1, H0);  // h2 = h1 + lrelu(bn(gat2(h1)))  (stored in H0)

  // ---- feed-forward ----
  k_gemm<true, true><<<dim3(DFFX / 64, (NN + 63) / 64), 256, 0, stream>>>(H0, ff_W1, ff_b1, FF1,
                                                                          NN, DIMX, DFFX);
  k_gemm<true, false><<<dim3(DIMX / 64, (NN + 63) / 64), 256, 0, stream>>>(FF1, ff_W2, ff_b2, G,
                                                                           NN, DFFX, DIMX);
  hipMemsetAsync(BNS, 0, 2 * DIMX * 4, stream);
  k_bnstats<<<128, 256, 0, stream>>>(G, BNS, NN);
  k_bnapply<true><<<(NN * DIMX + 255) / 256, 256, 0, stream>>>(G, H0, BNS, bn_g[2], bn_b[2],
                                                               d_out, NN, FLAG);
}

// Round 3
// 1810.413 us; speedup vs baseline: 1.3034x; 1.3034x over previous
//
#include <hip/hip_runtime.h>

#define NN 20000
#define NE 320000
#define DIMX 256
#define NHEADS 8
#define HC 32
#define EDIMX 32
#define DFFX 1024

__device__ __forceinline__ float b2f(unsigned short u) {
  return __uint_as_float(((unsigned)u) << 16);
}
__device__ __forceinline__ unsigned short f2b(float f) {
  unsigned u = __float_as_uint(f);
  u += 0x7FFF + ((u >> 16) & 1);
  return (unsigned short)(u >> 16);
}

// ---------------- dtype detect: 1 = inputs are f32, 0 = inputs are bf16 ----------------
__global__ void k_detect(const unsigned short* __restrict__ in, int* __restrict__ flag) {
  __shared__ int cnt_s;
  if (threadIdx.x == 0) cnt_s = 0;
  __syncthreads();
  int c = 0;
  for (int i = threadIdx.x; i < 4096; i += 256) {
    int ex = (in[i] >> 7) & 0xFF;
    if (ex >= 0xC6) c++;  // |x| >= 2^71 as bf16: impossible for real activations
  }
  atomicAdd(&cnt_s, c);
  __syncthreads();
  if (threadIdx.x == 0) flag[0] = (cnt_s > 64) ? 1 : 0;
}

// ---------------- universal input -> f32 convert ----------------
__global__ void k_cvt(const void* __restrict__ in, float* __restrict__ out, int n,
                      const int* __restrict__ flag) {
  int i = blockIdx.x * 256 + threadIdx.x;
  if (i >= n) return;
  if (flag[0]) out[i] = ((const float*)in)[i];
  else out[i] = b2f(((const unsigned short*)in)[i]);
}

// ---------------- fused multi-segment param convert ----------------
struct CvtArgs {
  const void* src[20];
  float* dst[20];
  int n[20];
};
__global__ void k_cvt_multi(CvtArgs a, const int* __restrict__ flag) {
  int seg = blockIdx.y;
  int n = a.n[seg];
  int i = blockIdx.x * 256 + threadIdx.x;
  if (i >= n) return;
  if (flag[0]) a.dst[seg][i] = ((const float*)a.src[seg])[i];
  else a.dst[seg][i] = b2f(((const unsigned short*)a.src[seg])[i]);
}

// ---------------- edge count (int atomics only) ----------------
__global__ void k_edge_count(const int* __restrict__ dst, int* __restrict__ cnt, int E) {
  int e = blockIdx.x * 256 + threadIdx.x;
  if (e >= E) return;
  atomicAdd(&cnt[dst[e]], 1);
}

// ---------------- single-block scan -> rowptr ----------------
__global__ void k_scan(const int* __restrict__ cnt, int* __restrict__ rowptr, int N) {
  __shared__ int sums[256];
  int t = threadIdx.x;
  int chunk = (N + 255) / 256;
  int lo = t * chunk, hi = lo + chunk;
  if (hi > N) hi = N;
  if (lo > N) lo = N;
  int s = 0;
  for (int n = lo; n < hi; n++) s += cnt[n] + 1;
  sums[t] = s;
  __syncthreads();
  for (int off = 1; off < 256; off <<= 1) {
    int v = (t >= off) ? sums[t - off] : 0;
    __syncthreads();
    sums[t] += v;
    __syncthreads();
  }
  int run = sums[t] - s;  // exclusive prefix
  for (int n = lo; n < hi; n++) { rowptr[n] = run; run += cnt[n] + 1; }
  if (t == 255) rowptr[N] = run;
}

// ---------------- CSR fill (edges + self loops) ----------------
__global__ void k_fill(const int* __restrict__ dst, const int* __restrict__ rowptr,
                       int* __restrict__ fill, int* __restrict__ eidx, int N, int E) {
  int t = blockIdx.x * 256 + threadIdx.x;
  if (t < E) {
    int d = dst[t];
    int pos = rowptr[d] + atomicAdd(&fill[d], 1);
    eidx[pos] = t;
  } else if (t < E + N) {
    int n = t - E;
    eidx[rowptr[n + 1] - 1] = E + n;  // self loop id
  }
}

// ---------------- loop_ea: per-node mean of incoming edge attrs (no atomics) ----------------
__global__ __launch_bounds__(256) void k_lea(const float* __restrict__ ew,
                                             const int* __restrict__ rowptr,
                                             const int* __restrict__ eidx,
                                             float* __restrict__ lea, int N) {
  int wave = threadIdx.x >> 6, lane = threadIdx.x & 63;
  int node = blockIdx.x * 4 + wave;
  if (node >= N) return;
  int begin = rowptr[node], end = rowptr[node + 1] - 1;  // exclude self-loop slot
  int ch = lane & 31, half = lane >> 5;
  float s = 0.f;
  for (int p = begin + half; p < end; p += 2) {
    int eid = eidx[p];
    s += ew[(size_t)eid * EDIMX + ch];
  }
  s += __shfl_xor(s, 32, 64);
  int deg = end - begin;
  if (lane < 32) lea[(size_t)node * EDIMX + ch] = s / (float)(deg > 0 ? deg : 1);
}

// ---------------- tiled GEMM: C[M,Nc] = A[M,K](f32) @ B[K,Nc](f32) ----------------
template <bool BIAS, bool RELU>
__global__ __launch_bounds__(256) void k_gemm(const float* __restrict__ A,
                                              const float* __restrict__ B,
                                              const float* __restrict__ bias,
                                              float* __restrict__ C, int M, int K, int Nc) {
  __shared__ float As[16][64];
  __shared__ float Bs[16][64];
  int tid = threadIdx.x;
  int tx = tid & 15, ty = tid >> 4;
  int m0 = blockIdx.y * 64, n0 = blockIdx.x * 64;
  int am = tid >> 2, ak = (tid & 3) * 4;
  int bk = tid >> 4, bn = (tid & 15) * 4;
  float4 acc[4];
  for (int i = 0; i < 4; i++) acc[i] = make_float4(0.f, 0.f, 0.f, 0.f);
  for (int k0 = 0; k0 < K; k0 += 16) {
    float4 av = make_float4(0.f, 0.f, 0.f, 0.f);
    if (m0 + am < M) av = *(const float4*)(A + (size_t)(m0 + am) * K + k0 + ak);
    As[ak + 0][am] = av.x; As[ak + 1][am] = av.y; As[ak + 2][am] = av.z; As[ak + 3][am] = av.w;
    *(float4*)&Bs[bk][bn] = *(const float4*)(B + (size_t)(k0 + bk) * Nc + n0 + bn);
    __syncthreads();
#pragma unroll
    for (int k = 0; k < 16; k++) {
      float4 a = *(const float4*)&As[k][ty * 4];
      float4 b = *(const float4*)&Bs[k][tx * 4];
      acc[0].x += a.x * b.x; acc[0].y += a.x * b.y; acc[0].z += a.x * b.z; acc[0].w += a.x * b.w;
      acc[1].x += a.y * b.x; acc[1].y += a.y * b.y; acc[1].z += a.y * b.z; acc[1].w += a.y * b.w;
      acc[2].x += a.z * b.x; acc[2].y += a.z * b.y; acc[2].z += a.z * b.z; acc[2].w += a.z * b.w;
      acc[3].x += a.w * b.x; acc[3].y += a.w * b.y; acc[3].z += a.w * b.z; acc[3].w += a.w * b.w;
    }
    __syncthreads();
  }
  float4 bia = make_float4(0.f, 0.f, 0.f, 0.f);
  if (BIAS) bia = *(const float4*)(bias + n0 + tx * 4);
  for (int i = 0; i < 4; i++) {
    int m = m0 + ty * 4 + i;
    if (m >= M) continue;
    float4 v = acc[i];
    if (BIAS) { v.x += bia.x; v.y += bia.y; v.z += bia.z; v.w += bia.w; }
    if (RELU) {
      v.x = fmaxf(v.x, 0.f); v.y = fmaxf(v.y, 0.f);
      v.z = fmaxf(v.z, 0.f); v.w = fmaxf(v.w, 0.f);
    }
    *(float4*)(C + (size_t)m * Nc + n0 + tx * 4) = v;
  }
}

// ---------------- per-edge attention score (1 wave = 1 edge) ----------------
__global__ __launch_bounds__(256) void k_score(const float* __restrict__ xl,
                                               const float* __restrict__ xr,
                                               const int* __restrict__ src,
                                               const int* __restrict__ dst,
                                               const float* __restrict__ ew,
                                               const float* __restrict__ loop_ea,
                                               const float* __restrict__ We,
                                               const float* __restrict__ att,
                                               float* __restrict__ score, int E, int N) {
  __shared__ float We_s[EDIMX * DIMX];  // 32 KB
  __shared__ float att_s[DIMX];         // 1 KB
  int tid = threadIdx.x;
  {
    const float4* Wg = (const float4*)We;
    float4* Ws = (float4*)We_s;
    for (int i = tid; i < EDIMX * DIMX / 4; i += 256) Ws[i] = Wg[i];
    att_s[tid] = att[tid];
  }
  __syncthreads();
  int wave = tid >> 6, lane = tid & 63;
  int eid = blockIdx.x * 4 + wave;
  if (eid >= E + N) return;
  int s, d;
  float eav = 0.f;
  if (eid < E) {
    s = src[eid]; d = dst[eid];
    if (lane < EDIMX) eav = ew[(size_t)eid * EDIMX + lane];
  } else {
    s = d = eid - E;
    if (lane < EDIMX) eav = loop_ea[(size_t)(eid - E) * EDIMX + lane];
  }
  int c0 = lane * 4;
  float ee0 = 0.f, ee1 = 0.f, ee2 = 0.f, ee3 = 0.f;
  const float4* Wrow = (const float4*)We_s;
#pragma unroll
  for (int k = 0; k < EDIMX; k++) {
    float a = __shfl(eav, k, 64);
    float4 w = Wrow[k * 64 + lane];
    ee0 += a * w.x; ee1 += a * w.y; ee2 += a * w.z; ee3 += a * w.w;
  }
  float4 vl = *(const float4*)(xl + (size_t)s * DIMX + c0);
  float4 vr = *(const float4*)(xr + (size_t)d * DIMX + c0);
  float z0 = vl.x + vr.x + ee0, z1 = vl.y + vr.y + ee1;
  float z2 = vl.z + vr.z + ee2, z3 = vl.w + vr.w + ee3;
  z0 = z0 > 0.f ? z0 : 0.2f * z0; z1 = z1 > 0.f ? z1 : 0.2f * z1;
  z2 = z2 > 0.f ? z2 : 0.2f * z2; z3 = z3 > 0.f ? z3 : 0.2f * z3;
  float4 a4 = *(const float4*)&att_s[c0];
  float p = z0 * a4.x + z1 * a4.y + z2 * a4.z + z3 * a4.w;
  p += __shfl_xor(p, 1, 64);
  p += __shfl_xor(p, 2, 64);
  p += __shfl_xor(p, 4, 64);
  if ((lane & 7) == 0) score[(size_t)eid * NHEADS + (lane >> 3)] = p;
}

// ---------------- per-node segment softmax (1 wave = 1 node) ----------------
__global__ __launch_bounds__(256) void k_softmax(const int* __restrict__ rowptr,
                                                 const int* __restrict__ eidx,
                                                 float* __restrict__ score, int N) {
  int wave = threadIdx.x >> 6, lane = threadIdx.x & 63;
  int node = blockIdx.x * 4 + wave;
  if (node >= N) return;
  int begin = rowptr[node], end = rowptr[node + 1], len = end - begin;
  int head = lane & 7, slot = lane >> 3;
  float m = -3.4e38f;
  for (int base = 0; base < len; base += 8) {
    int idx = base + slot;
    if (idx < len) {
      int eid = eidx[begin + idx];
      m = fmaxf(m, score[(size_t)eid * NHEADS + head]);
    }
  }
  m = fmaxf(m, __shfl_xor(m, 8, 64));
  m = fmaxf(m, __shfl_xor(m, 16, 64));
  m = fmaxf(m, __shfl_xor(m, 32, 64));
  float ssum = 0.f;
  for (int base = 0; base < len; base += 8) {
    int idx = base + slot;
    if (idx < len) {
      int eid = eidx[begin + idx];
      ssum += expf(score[(size_t)eid * NHEADS + head] - m);
    }
  }
  ssum += __shfl_xor(ssum, 8, 64);
  ssum += __shfl_xor(ssum, 16, 64);
  ssum += __shfl_xor(ssum, 32, 64);
  float inv = 1.f / ssum;
  for (int base = 0; base < len; base += 8) {
    int idx = base + slot;
    if (idx < len) {
      int eid = eidx[begin + idx];
      size_t p = (size_t)eid * NHEADS + head;
      score[p] = expf(score[p] - m) * inv;
    }
  }
}

// ---------------- per-node aggregation (1 wave = 1 node) ----------------
__global__ __launch_bounds__(256) void k_aggregate(const float* __restrict__ xl,
                                                   const float* __restrict__ alpha,
                                                   const int* __restrict__ rowptr,
                                                   const int* __restrict__ eidx,
                                                   const int* __restrict__ src,
                                                   const float* __restrict__ bias,
                                                   float* __restrict__ out, int N, int E) {
  int wave = threadIdx.x >> 6, lane = threadIdx.x & 63;
  int node = blockIdx.x * 4 + wave;
  if (node >= N) return;
  int begin = rowptr[node], end = rowptr[node + 1];
  int head = lane >> 3;
  const float4* xl4 = (const float4*)xl;
  float4 acc = make_float4(0.f, 0.f, 0.f, 0.f);
  for (int p = begin; p < end; p++) {
    int eid = eidx[p];
    int s = (eid < E) ? src[eid] : node;
    float a = alpha[(size_t)eid * NHEADS + head];
    float4 v = xl4[(size_t)s * 64 + lane];
    acc.x += a * v.x; acc.y += a * v.y; acc.z += a * v.z; acc.w += a * v.w;
  }
  float4 bia = *(const float4*)(bias + lane * 4);
  acc.x += bia.x; acc.y += bia.y; acc.z += bia.z; acc.w += bia.w;
  ((float4*)out)[(size_t)node * 64 + lane] = acc;
}

// ---------------- BN stats (sum, sumsq per channel) ----------------
__global__ __launch_bounds__(256) void k_bnstats(const float* __restrict__ x,
                                                 float* __restrict__ sums, int N) {
  int c = threadIdx.x;
  float s = 0.f, sq = 0.f;
  for (int n = blockIdx.x; n < N; n += gridDim.x) {
    float v = x[(size_t)n * DIMX + c];
    s += v; sq += v * v;
  }
  atomicAdd(&sums[c], s);
  atomicAdd(&sums[DIMX + c], sq);
}

// ---------------- BN + leaky_relu(0.01) + residual ----------------
template <bool FINAL>
__global__ __launch_bounds__(256) void k_bnapply(const float* __restrict__ x,
                                                 const float* __restrict__ res,
                                                 const float* __restrict__ sums,
                                                 const float* __restrict__ g,
                                                 const float* __restrict__ b,
                                                 void* __restrict__ out, int N,
                                                 const int* __restrict__ flag) {
  int i = blockIdx.x * 256 + threadIdx.x;
  if (i >= N * DIMX) return;
  int c = i & (DIMX - 1);
  float invn = 1.f / (float)N;
  float mu = sums[c] * invn;
  float var = sums[DIMX + c] * invn - mu * mu;
  float rstd = rsqrtf(var + 1e-5f);
  float y = (x[i] - mu) * rstd * g[c] + b[c];
  y = y > 0.f ? y : 0.01f * y;
  y += res[i];
  if (FINAL) {
    if (flag[0]) ((float*)out)[i] = y;
    else ((unsigned short*)out)[i] = f2b(y);
  } else {
    ((float*)out)[i] = y;
  }
}

extern "C" void kernel_launch(void* const* d_in, const int* in_sizes, int n_in,
                              void* d_out, int out_size, void* d_ws, size_t ws_size,
                              hipStream_t stream) {
  (void)in_sizes; (void)n_in; (void)out_size; (void)ws_size;
  const int* ei = (const int*)d_in[1];
  const int* srcp = ei;
  const int* dstp = ei + NE;

  char* w = (char*)d_ws;
  auto alloc = [&](size_t bytes) {
    char* p = w;
    w += (bytes + 255) & ~(size_t)255;
    return p;
  };
  float* H0 = (float*)alloc((size_t)NN * DIMX * 4);
  float* H1 = (float*)alloc((size_t)NN * DIMX * 4);
  float* G = (float*)alloc((size_t)NN * DIMX * 4);
  float* XL = (float*)alloc((size_t)NN * DIMX * 4);
  float* XR = (float*)alloc((size_t)NN * DIMX * 4);
  float* SCORE = (float*)alloc((size_t)(NE + NN) * NHEADS * 4);
  float* LEA = (float*)alloc((size_t)NN * EDIMX * 4);
  float* EWF = (float*)alloc((size_t)NE * EDIMX * 4);
  float* PAR = (float*)alloc((size_t)806656 * 4);
  int* CNT = (int*)alloc((size_t)NN * 4);
  int* ROWPTR = (int*)alloc((size_t)(NN + 1) * 4);
  int* FILL = (int*)alloc((size_t)NN * 4);
  int* EIDX = (int*)alloc((size_t)(NE + NN) * 4);
  float* BNS = (float*)alloc(2 * DIMX * 4);
  int* FLAG = (int*)alloc(256);
  float* FF1 = (float*)alloc((size_t)NN * DFFX * 4);

  // ---- dtype detect + convert everything to f32 ----
  k_detect<<<1, 256, 0, stream>>>((const unsigned short*)d_in[0], FLAG);
  k_cvt<<<(NN * DIMX + 255) / 256, 256, 0, stream>>>(d_in[0], H0, NN * DIMX, FLAG);
  k_cvt<<<(NE * EDIMX + 255) / 256, 256, 0, stream>>>(d_in[2], EWF, NE * EDIMX, FLAG);
  static const int psz[20] = {65536, 65536, 8192, 256, 256,
                              65536, 65536, 8192, 256, 256,
                              256, 256, 256, 256, 256, 256,
                              262144, 1024, 262144, 256};
  float* pp[20];
  {
    CvtArgs ca;
    int off = 0;
    for (int i = 0; i < 20; i++) {
      pp[i] = PAR + off;
      off += psz[i];
      ca.src[i] = d_in[3 + i];
      ca.dst[i] = pp[i];
      ca.n[i] = psz[i];
    }
    k_cvt_multi<<<dim3(262144 / 256, 20), 256, 0, stream>>>(ca, FLAG);
  }
  const float* g_Wl[2] = {pp[0], pp[5]};
  const float* g_Wr[2] = {pp[1], pp[6]};
  const float* g_We[2] = {pp[2], pp[7]};
  const float* g_att[2] = {pp[3], pp[8]};
  const float* g_b[2] = {pp[4], pp[9]};
  const float* bn_g[3] = {pp[10], pp[12], pp[14]};
  const float* bn_b[3] = {pp[11], pp[13], pp[15]};
  const float* ff_W1 = pp[16];
  const float* ff_b1 = pp[17];
  const float* ff_W2 = pp[18];
  const float* ff_b2 = pp[19];

  // ---- graph structure (shared by both GAT layers) ----
  hipMemsetAsync(CNT, 0, (size_t)NN * 4, stream);
  hipMemsetAsync(FILL, 0, (size_t)NN * 4, stream);
  k_edge_count<<<(NE + 255) / 256, 256, 0, stream>>>(dstp, CNT, NE);
  k_scan<<<1, 256, 0, stream>>>(CNT, ROWPTR, NN);
  k_fill<<<(NE + NN + 255) / 256, 256, 0, stream>>>(dstp, ROWPTR, FILL, EIDX, NN, NE);
  k_lea<<<(NN + 3) / 4, 256, 0, stream>>>(EWF, ROWPTR, EIDX, LEA, NN);

  auto run_gat = [&](const float* x, int li, int bi, float* hout) {
    dim3 gg(DIMX / 64, (NN + 63) / 64);
    k_gemm<false, false><<<gg, 256, 0, stream>>>(x, g_Wl[li], nullptr, XL, NN, DIMX, DIMX);
    k_gemm<false, false><<<gg, 256, 0, stream>>>(x, g_Wr[li], nullptr, XR, NN, DIMX, DIMX);
    k_score<<<(NE + NN + 3) / 4, 256, 0, stream>>>(XL, XR, srcp, dstp, EWF, LEA, g_We[li],
                                                   g_att[li], SCORE, NE, NN);
    k_softmax<<<(NN + 3) / 4, 256, 0, stream>>>(ROWPTR, EIDX, SCORE, NN);
    k_aggregate<<<(NN + 3) / 4, 256, 0, stream>>>(XL, SCORE, ROWPTR, EIDX, srcp, g_b[li], G,
                                                  NN, NE);
    hipMemsetAsync(BNS, 0, 2 * DIMX * 4, stream);
    k_bnstats<<<128, 256, 0, stream>>>(G, BNS, NN);
    k_bnapply<false><<<(NN * DIMX + 255) / 256, 256, 0, stream>>>(G, x, BNS, bn_g[bi], bn_b[bi],
                                                                  hout, NN, FLAG);
  };

  run_gat(H0, 0, 0, H1);  // h1 = nf + lrelu(bn(gat1(nf)))
  run_gat(H1, 1, 1, H0);  // h2 = h1 + lrelu(bn(gat2(h1)))  (stored in H0)

  // ---- feed-forward ----
  k_gemm<true, true><<<dim3(DFFX / 64, (NN + 63) / 64), 256, 0, stream>>>(H0, ff_W1, ff_b1, FF1,
                                                                          NN, DIMX, DFFX);
  k_gemm<true, false><<<dim3(DIMX / 64, (NN + 63) / 64), 256, 0, stream>>>(FF1, ff_W2, ff_b2, G,
                                                                           NN, DFFX, DIMX);
  hipMemsetAsync(BNS, 0, 2 * DIMX * 4, stream);
  k_bnstats<<<128, 256, 0, stream>>>(G, BNS, NN);
  k_bnapply<true><<<(NN * DIMX + 255) / 256, 256, 0, stream>>>(G, H0, BNS, bn_g[2], bn_b[2],
                                                               d_out, NN, FLAG);
}

// Round 4
// 1488.689 us; speedup vs baseline: 1.5851x; 1.2161x over previous
//
#include <hip/hip_runtime.h>

#define NN 20000
#define NE 320000
#define DIMX 256
#define NHEADS 8
#define HC 32
#define EDIMX 32
#define DFFX 1024

__device__ __forceinline__ float b2f(unsigned short u) {
  return __uint_as_float(((unsigned)u) << 16);
}
__device__ __forceinline__ unsigned short f2b(float f) {
  unsigned u = __float_as_uint(f);
  u += 0x7FFF + ((u >> 16) & 1);
  return (unsigned short)(u >> 16);
}

// ---------------- dtype detect: 1 = inputs are f32, 0 = inputs are bf16 ----------------
__global__ void k_detect(const unsigned short* __restrict__ in, int* __restrict__ flag) {
  __shared__ int cnt_s;
  if (threadIdx.x == 0) cnt_s = 0;
  __syncthreads();
  int c = 0;
  for (int i = threadIdx.x; i < 4096; i += 256) {
    int ex = (in[i] >> 7) & 0xFF;
    if (ex >= 0xC6) c++;  // |x| >= 2^71 as bf16: impossible for real activations
  }
  atomicAdd(&cnt_s, c);
  __syncthreads();
  if (threadIdx.x == 0) flag[0] = (cnt_s > 64) ? 1 : 0;
}

// ---------------- universal input -> f32 convert ----------------
__global__ void k_cvt(const void* __restrict__ in, float* __restrict__ out, int n,
                      const int* __restrict__ flag) {
  int i = blockIdx.x * 256 + threadIdx.x;
  if (i >= n) return;
  if (flag[0]) out[i] = ((const float*)in)[i];
  else out[i] = b2f(((const unsigned short*)in)[i]);
}

// ---------------- fused multi-segment param convert ----------------
struct CvtArgs {
  const void* src[20];
  float* dst[20];
  int n[20];
};
__global__ void k_cvt_multi(CvtArgs a, const int* __restrict__ flag) {
  int seg = blockIdx.y;
  int n = a.n[seg];
  int i = blockIdx.x * 256 + threadIdx.x;
  if (i >= n) return;
  if (flag[0]) a.dst[seg][i] = ((const float*)a.src[seg])[i];
  else a.dst[seg][i] = b2f(((const unsigned short*)a.src[seg])[i]);
}

// ---------------- edge count (int atomics only) ----------------
__global__ void k_edge_count(const int* __restrict__ dst, int* __restrict__ cnt, int E) {
  int e = blockIdx.x * 256 + threadIdx.x;
  if (e >= E) return;
  atomicAdd(&cnt[dst[e]], 1);
}

// ---------------- single-block scan -> rowptr ----------------
__global__ void k_scan(const int* __restrict__ cnt, int* __restrict__ rowptr, int N) {
  __shared__ int sums[256];
  int t = threadIdx.x;
  int chunk = (N + 255) / 256;
  int lo = t * chunk, hi = lo + chunk;
  if (hi > N) hi = N;
  if (lo > N) lo = N;
  int s = 0;
  for (int n = lo; n < hi; n++) s += cnt[n] + 1;
  sums[t] = s;
  __syncthreads();
  for (int off = 1; off < 256; off <<= 1) {
    int v = (t >= off) ? sums[t - off] : 0;
    __syncthreads();
    sums[t] += v;
    __syncthreads();
  }
  int run = sums[t] - s;  // exclusive prefix
  for (int n = lo; n < hi; n++) { rowptr[n] = run; run += cnt[n] + 1; }
  if (t == 255) rowptr[N] = run;
}

// ---------------- CSR fill (edges + self loops) ----------------
__global__ void k_fill(const int* __restrict__ dst, const int* __restrict__ rowptr,
                       int* __restrict__ fill, int* __restrict__ eidx, int N, int E) {
  int t = blockIdx.x * 256 + threadIdx.x;
  if (t < E) {
    int d = dst[t];
    int pos = rowptr[d] + atomicAdd(&fill[d], 1);
    eidx[pos] = t;
  } else if (t < E + N) {
    int n = t - E;
    eidx[rowptr[n + 1] - 1] = E + n;  // self loop id
  }
}

// ---------------- loop_ea: per-node mean of incoming edge attrs (no atomics) ----------------
__global__ __launch_bounds__(256) void k_lea(const float* __restrict__ ew,
                                             const int* __restrict__ rowptr,
                                             const int* __restrict__ eidx,
                                             float* __restrict__ lea, int N) {
  int wave = threadIdx.x >> 6, lane = threadIdx.x & 63;
  int node = blockIdx.x * 4 + wave;
  if (node >= N) return;
  int begin = rowptr[node], end = rowptr[node + 1] - 1;  // exclude self-loop slot
  int ch = lane & 31, half = lane >> 5;
  float s = 0.f;
  for (int p = begin + half; p < end; p += 2) {
    int eid = eidx[p];
    s += ew[(size_t)eid * EDIMX + ch];
  }
  s += __shfl_xor(s, 32, 64);
  int deg = end - begin;
  if (lane < 32) lea[(size_t)node * EDIMX + ch] = s / (float)(deg > 0 ? deg : 1);
}

// ---------------- tiled GEMM: C[M,Nc] = A[M,K](f32) @ B[K,Nc](f32) ----------------
template <bool BIAS, bool RELU>
__global__ __launch_bounds__(256) void k_gemm(const float* __restrict__ A,
                                              const float* __restrict__ B,
                                              const float* __restrict__ bias,
                                              float* __restrict__ C, int M, int K, int Nc) {
  __shared__ float As[16][64];
  __shared__ float Bs[16][64];
  int tid = threadIdx.x;
  int tx = tid & 15, ty = tid >> 4;
  int m0 = blockIdx.y * 64, n0 = blockIdx.x * 64;
  int am = tid >> 2, ak = (tid & 3) * 4;
  int bk = tid >> 4, bn = (tid & 15) * 4;
  float4 acc[4];
  for (int i = 0; i < 4; i++) acc[i] = make_float4(0.f, 0.f, 0.f, 0.f);
  for (int k0 = 0; k0 < K; k0 += 16) {
    float4 av = make_float4(0.f, 0.f, 0.f, 0.f);
    if (m0 + am < M) av = *(const float4*)(A + (size_t)(m0 + am) * K + k0 + ak);
    As[ak + 0][am] = av.x; As[ak + 1][am] = av.y; As[ak + 2][am] = av.z; As[ak + 3][am] = av.w;
    *(float4*)&Bs[bk][bn] = *(const float4*)(B + (size_t)(k0 + bk) * Nc + n0 + bn);
    __syncthreads();
#pragma unroll
    for (int k = 0; k < 16; k++) {
      float4 a = *(const float4*)&As[k][ty * 4];
      float4 b = *(const float4*)&Bs[k][tx * 4];
      acc[0].x += a.x * b.x; acc[0].y += a.x * b.y; acc[0].z += a.x * b.z; acc[0].w += a.x * b.w;
      acc[1].x += a.y * b.x; acc[1].y += a.y * b.y; acc[1].z += a.y * b.z; acc[1].w += a.y * b.w;
      acc[2].x += a.z * b.x; acc[2].y += a.z * b.y; acc[2].z += a.z * b.z; acc[2].w += a.z * b.w;
      acc[3].x += a.w * b.x; acc[3].y += a.w * b.y; acc[3].z += a.w * b.z; acc[3].w += a.w * b.w;
    }
    __syncthreads();
  }
  float4 bia = make_float4(0.f, 0.f, 0.f, 0.f);
  if (BIAS) bia = *(const float4*)(bias + n0 + tx * 4);
  for (int i = 0; i < 4; i++) {
    int m = m0 + ty * 4 + i;
    if (m >= M) continue;
    float4 v = acc[i];
    if (BIAS) { v.x += bia.x; v.y += bia.y; v.z += bia.z; v.w += bia.w; }
    if (RELU) {
      v.x = fmaxf(v.x, 0.f); v.y = fmaxf(v.y, 0.f);
      v.z = fmaxf(v.z, 0.f); v.w = fmaxf(v.w, 0.f);
    }
    *(float4*)(C + (size_t)m * Nc + n0 + tx * 4) = v;
  }
}

// ---------------- fused GATv2 attention: score + online-softmax + aggregate ----------------
// 1 wave = 1 dst node; lane owns channels [lane*4, lane*4+4), head = lane>>3.
__global__ __launch_bounds__(256) void k_gat_fused(const float* __restrict__ xl,
                                                   const float* __restrict__ xr,
                                                   const float* __restrict__ ew,
                                                   const float* __restrict__ lea,
                                                   const float* __restrict__ We,
                                                   const float* __restrict__ att,
                                                   const float* __restrict__ bias,
                                                   const int* __restrict__ rowptr,
                                                   const int* __restrict__ eidx,
                                                   const int* __restrict__ src,
                                                   float* __restrict__ out, int N, int E) {
  __shared__ float We_s[EDIMX * DIMX];  // 32 KB
  __shared__ float att_s[DIMX];
  int tid = threadIdx.x;
  {
    const float4* Wg = (const float4*)We;
    float4* Ws = (float4*)We_s;
    for (int i = tid; i < EDIMX * DIMX / 4; i += 256) Ws[i] = Wg[i];
    att_s[tid] = att[tid];
  }
  __syncthreads();
  int wave = tid >> 6, lane = tid & 63;
  int node = blockIdx.x * 4 + wave;
  if (node >= N) return;
  int begin = rowptr[node], end = rowptr[node + 1];
  int c0 = lane * 4;
  float4 vr = *(const float4*)(xr + (size_t)node * DIMX + c0);  // loaded ONCE per node
  float4 a4 = *(const float4*)&att_s[c0];
  const float4* Wrow = (const float4*)We_s;
  float m = -3.4e38f, l = 0.f;
  float4 acc = make_float4(0.f, 0.f, 0.f, 0.f);
  for (int p = begin; p < end; p++) {
    int eid = eidx[p];
    int s;
    const float* earow;
    if (eid < E) {
      s = src[eid];
      earow = ew + (size_t)eid * EDIMX;
    } else {
      s = node;
      earow = lea + (size_t)node * EDIMX;
    }
    float eav = (lane < EDIMX) ? earow[lane] : 0.f;
    float4 vl = *(const float4*)(xl + (size_t)s * DIMX + c0);
    float ee0 = 0.f, ee1 = 0.f, ee2 = 0.f, ee3 = 0.f;
#pragma unroll
    for (int k = 0; k < EDIMX; k++) {
      float a = __shfl(eav, k, 64);
      float4 wv = Wrow[k * 64 + lane];
      ee0 += a * wv.x; ee1 += a * wv.y; ee2 += a * wv.z; ee3 += a * wv.w;
    }
    float z0 = vl.x + vr.x + ee0, z1 = vl.y + vr.y + ee1;
    float z2 = vl.z + vr.z + ee2, z3 = vl.w + vr.w + ee3;
    z0 = z0 > 0.f ? z0 : 0.2f * z0; z1 = z1 > 0.f ? z1 : 0.2f * z1;
    z2 = z2 > 0.f ? z2 : 0.2f * z2; z3 = z3 > 0.f ? z3 : 0.2f * z3;
    float sc = z0 * a4.x + z1 * a4.y + z2 * a4.z + z3 * a4.w;
    sc += __shfl_xor(sc, 1, 64);
    sc += __shfl_xor(sc, 2, 64);
    sc += __shfl_xor(sc, 4, 64);  // now all 8 lanes of a head hold the head's score
    float mn = fmaxf(m, sc);
    float scale = __expf(m - mn);  // 0 on first iteration (m = -inf)
    float wgt = __expf(sc - mn);
    l = l * scale + wgt;
    acc.x = acc.x * scale + wgt * vl.x;
    acc.y = acc.y * scale + wgt * vl.y;
    acc.z = acc.z * scale + wgt * vl.z;
    acc.w = acc.w * scale + wgt * vl.w;
    m = mn;
  }
  float inv = 1.f / l;
  float4 bia = *(const float4*)(bias + c0);
  acc.x = acc.x * inv + bia.x;
  acc.y = acc.y * inv + bia.y;
  acc.z = acc.z * inv + bia.z;
  acc.w = acc.w * inv + bia.w;
  ((float4*)out)[(size_t)node * 64 + lane] = acc;
}

// ---------------- BN stats (sum, sumsq per channel) ----------------
__global__ __launch_bounds__(256) void k_bnstats(const float* __restrict__ x,
                                                 float* __restrict__ sums, int N) {
  int c = threadIdx.x;
  float s = 0.f, sq = 0.f;
  for (int n = blockIdx.x; n < N; n += gridDim.x) {
    float v = x[(size_t)n * DIMX + c];
    s += v; sq += v * v;
  }
  atomicAdd(&sums[c], s);
  atomicAdd(&sums[DIMX + c], sq);
}

// ---------------- BN + leaky_relu(0.01) + residual ----------------
template <bool FINAL>
__global__ __launch_bounds__(256) void k_bnapply(const float* __restrict__ x,
                                                 const float* __restrict__ res,
                                                 const float* __restrict__ sums,
                                                 const float* __restrict__ g,
                                                 const float* __restrict__ b,
                                                 void* __restrict__ out, int N,
                                                 const int* __restrict__ flag) {
  int i = blockIdx.x * 256 + threadIdx.x;
  if (i >= N * DIMX) return;
  int c = i & (DIMX - 1);
  float invn = 1.f / (float)N;
  float mu = sums[c] * invn;
  float var = sums[DIMX + c] * invn - mu * mu;
  float rstd = rsqrtf(var + 1e-5f);
  float y = (x[i] - mu) * rstd * g[c] + b[c];
  y = y > 0.f ? y : 0.01f * y;
  y += res[i];
  if (FINAL) {
    if (flag[0]) ((float*)out)[i] = y;
    else ((unsigned short*)out)[i] = f2b(y);
  } else {
    ((float*)out)[i] = y;
  }
}

extern "C" void kernel_launch(void* const* d_in, const int* in_sizes, int n_in,
                              void* d_out, int out_size, void* d_ws, size_t ws_size,
                              hipStream_t stream) {
  (void)in_sizes; (void)n_in; (void)out_size; (void)ws_size;
  const int* ei = (const int*)d_in[1];
  const int* srcp = ei;
  const int* dstp = ei + NE;

  char* w = (char*)d_ws;
  auto alloc = [&](size_t bytes) {
    char* p = w;
    w += (bytes + 255) & ~(size_t)255;
    return p;
  };
  float* H0 = (float*)alloc((size_t)NN * DIMX * 4);
  float* H1 = (float*)alloc((size_t)NN * DIMX * 4);
  float* G = (float*)alloc((size_t)NN * DIMX * 4);
  float* XL = (float*)alloc((size_t)NN * DIMX * 4);
  float* XR = (float*)alloc((size_t)NN * DIMX * 4);
  float* LEA = (float*)alloc((size_t)NN * EDIMX * 4);
  float* EWF = (float*)alloc((size_t)NE * EDIMX * 4);
  float* PAR = (float*)alloc((size_t)806656 * 4);
  int* CNT = (int*)alloc((size_t)NN * 4);
  int* ROWPTR = (int*)alloc((size_t)(NN + 1) * 4);
  int* FILL = (int*)alloc((size_t)NN * 4);
  int* EIDX = (int*)alloc((size_t)(NE + NN) * 4);
  float* BNS = (float*)alloc(2 * DIMX * 4);
  int* FLAG = (int*)alloc(256);
  float* FF1 = (float*)alloc((size_t)NN * DFFX * 4);

  // ---- dtype detect + convert everything to f32 ----
  k_detect<<<1, 256, 0, stream>>>((const unsigned short*)d_in[0], FLAG);
  k_cvt<<<(NN * DIMX + 255) / 256, 256, 0, stream>>>(d_in[0], H0, NN * DIMX, FLAG);
  k_cvt<<<(NE * EDIMX + 255) / 256, 256, 0, stream>>>(d_in[2], EWF, NE * EDIMX, FLAG);
  static const int psz[20] = {65536, 65536, 8192, 256, 256,
                              65536, 65536, 8192, 256, 256,
                              256, 256, 256, 256, 256, 256,
                              262144, 1024, 262144, 256};
  float* pp[20];
  {
    CvtArgs ca;
    int off = 0;
    for (int i = 0; i < 20; i++) {
      pp[i] = PAR + off;
      off += psz[i];
      ca.src[i] = d_in[3 + i];
      ca.dst[i] = pp[i];
      ca.n[i] = psz[i];
    }
    k_cvt_multi<<<dim3(262144 / 256, 20), 256, 0, stream>>>(ca, FLAG);
  }
  const float* g_Wl[2] = {pp[0], pp[5]};
  const float* g_Wr[2] = {pp[1], pp[6]};
  const float* g_We[2] = {pp[2], pp[7]};
  const float* g_att[2] = {pp[3], pp[8]};
  const float* g_b[2] = {pp[4], pp[9]};
  const float* bn_g[3] = {pp[10], pp[12], pp[14]};
  const float* bn_b[3] = {pp[11], pp[13], pp[15]};
  const float* ff_W1 = pp[16];
  const float* ff_b1 = pp[17];
  const float* ff_W2 = pp[18];
  const float* ff_b2 = pp[19];

  // ---- graph structure (shared by both GAT layers) ----
  hipMemsetAsync(CNT, 0, (size_t)NN * 4, stream);
  hipMemsetAsync(FILL, 0, (size_t)NN * 4, stream);
  k_edge_count<<<(NE + 255) / 256, 256, 0, stream>>>(dstp, CNT, NE);
  k_scan<<<1, 256, 0, stream>>>(CNT, ROWPTR, NN);
  k_fill<<<(NE + NN + 255) / 256, 256, 0, stream>>>(dstp, ROWPTR, FILL, EIDX, NN, NE);
  k_lea<<<(NN + 3) / 4, 256, 0, stream>>>(EWF, ROWPTR, EIDX, LEA, NN);

  auto run_gat = [&](const float* x, int li, int bi, float* hout) {
    dim3 gg(DIMX / 64, (NN + 63) / 64);
    k_gemm<false, false><<<gg, 256, 0, stream>>>(x, g_Wl[li], nullptr, XL, NN, DIMX, DIMX);
    k_gemm<false, false><<<gg, 256, 0, stream>>>(x, g_Wr[li], nullptr, XR, NN, DIMX, DIMX);
    k_gat_fused<<<(NN + 3) / 4, 256, 0, stream>>>(XL, XR, EWF, LEA, g_We[li], g_att[li],
                                                  g_b[li], ROWPTR, EIDX, srcp, G, NN, NE);
    hipMemsetAsync(BNS, 0, 2 * DIMX * 4, stream);
    k_bnstats<<<128, 256, 0, stream>>>(G, BNS, NN);
    k_bnapply<false><<<(NN * DIMX + 255) / 256, 256, 0, stream>>>(G, x, BNS, bn_g[bi], bn_b[bi],
                                                                  hout, NN, FLAG);
  };

  run_gat(H0, 0, 0, H1);  // h1 = nf + lrelu(bn(gat1(nf)))
  run_gat(H1, 1, 1, H0);  // h2 = h1 + lrelu(bn(gat2(h1)))  (stored in H0)

  // ---- feed-forward ----
  k_gemm<true, true><<<dim3(DFFX / 64, (NN + 63) / 64), 256, 0, stream>>>(H0, ff_W1, ff_b1, FF1,
                                                                          NN, DIMX, DFFX);
  k_gemm<true, false><<<dim3(DIMX / 64, (NN + 63) / 64), 256, 0, stream>>>(FF1, ff_W2, ff_b2, G,
                                                                           NN, DFFX, DIMX);
  hipMemsetAsync(BNS, 0, 2 * DIMX * 4, stream);
  k_bnstats<<<128, 256, 0, stream>>>(G, BNS, NN);
  k_bnapply<true><<<(NN * DIMX + 255) / 256, 256, 0, stream>>>(G, H0, BNS, bn_g[2], bn_b[2],
                                                               d_out, NN, FLAG);
}

// Round 5
// 1197.302 us; speedup vs baseline: 1.9708x; 1.2434x over previous
//
#include <hip/hip_runtime.h>

#define NN 20000
#define NE 320000
#define DIMX 256
#define NHEADS 8
#define HC 32
#define EDIMX 32
#define DFFX 1024

using f32x4 = __attribute__((ext_vector_type(4))) float;
using bfrag = __attribute__((ext_vector_type(8))) short;  // 8 bf16 = 4 VGPRs

__device__ __forceinline__ float b2f(unsigned short u) {
  return __uint_as_float(((unsigned)u) << 16);
}
__device__ __forceinline__ unsigned short f2b(float f) {
  unsigned u = __float_as_uint(f);
  u += 0x7FFF + ((u >> 16) & 1);
  return (unsigned short)(u >> 16);
}

// ---------------- dtype detect: 1 = inputs are f32, 0 = inputs are bf16 ----------------
__global__ void k_detect(const unsigned short* __restrict__ in, int* __restrict__ flag) {
  __shared__ int cnt_s;
  if (threadIdx.x == 0) cnt_s = 0;
  __syncthreads();
  int c = 0;
  for (int i = threadIdx.x; i < 4096; i += 256) {
    int ex = (in[i] >> 7) & 0xFF;
    if (ex >= 0xC6) c++;  // |x| >= 2^71 as bf16: impossible for real activations
  }
  atomicAdd(&cnt_s, c);
  __syncthreads();
  if (threadIdx.x == 0) flag[0] = (cnt_s > 64) ? 1 : 0;
}

// ---------------- universal input -> f32 convert ----------------
__global__ void k_cvt(const void* __restrict__ in, float* __restrict__ out, int n,
                      const int* __restrict__ flag) {
  int i = blockIdx.x * 256 + threadIdx.x;
  if (i >= n) return;
  if (flag[0]) out[i] = ((const float*)in)[i];
  else out[i] = b2f(((const unsigned short*)in)[i]);
}

// ---------------- input -> f32 + bf16 shadow ----------------
__global__ void k_cvt_dual(const void* __restrict__ in, float* __restrict__ outf,
                           unsigned short* __restrict__ outb, int n,
                           const int* __restrict__ flag) {
  int i = blockIdx.x * 256 + threadIdx.x;
  if (i >= n) return;
  if (flag[0]) {
    float v = ((const float*)in)[i];
    outf[i] = v;
    outb[i] = f2b(v);
  } else {
    unsigned short u = ((const unsigned short*)in)[i];
    outf[i] = b2f(u);
    outb[i] = u;
  }
}

// ---------------- fused multi-segment param convert ----------------
struct CvtArgs {
  const void* src[20];
  float* dst[20];
  int n[20];
};
__global__ void k_cvt_multi(CvtArgs a, const int* __restrict__ flag) {
  int seg = blockIdx.y;
  int n = a.n[seg];
  int i = blockIdx.x * 256 + threadIdx.x;
  if (i >= n) return;
  if (flag[0]) a.dst[seg][i] = ((const float*)a.src[seg])[i];
  else a.dst[seg][i] = b2f(((const unsigned short*)a.src[seg])[i]);
}

// ---------------- f32 [K][N] -> bf16 [N][K] transpose ----------------
__global__ __launch_bounds__(256) void k_transpose(const float* __restrict__ in,
                                                   unsigned short* __restrict__ out,
                                                   int K, int N) {
  __shared__ float t[32][33];
  int n0 = blockIdx.x * 32, k0 = blockIdx.y * 32;
  int tx = threadIdx.x & 31, ty = threadIdx.x >> 5;  // 32 x 8
#pragma unroll
  for (int i = 0; i < 4; i++)
    t[ty + i * 8][tx] = in[(size_t)(k0 + ty + i * 8) * N + n0 + tx];
  __syncthreads();
#pragma unroll
  for (int i = 0; i < 4; i++)
    out[(size_t)(n0 + ty + i * 8) * K + k0 + tx] = f2b(t[tx][ty + i * 8]);
}

// ---------------- edge count (int atomics only) ----------------
__global__ void k_edge_count(const int* __restrict__ dst, int* __restrict__ cnt, int E) {
  int e = blockIdx.x * 256 + threadIdx.x;
  if (e >= E) return;
  atomicAdd(&cnt[dst[e]], 1);
}

// ---------------- single-block scan -> rowptr ----------------
__global__ void k_scan(const int* __restrict__ cnt, int* __restrict__ rowptr, int N) {
  __shared__ int sums[256];
  int t = threadIdx.x;
  int chunk = (N + 255) / 256;
  int lo = t * chunk, hi = lo + chunk;
  if (hi > N) hi = N;
  if (lo > N) lo = N;
  int s = 0;
  for (int n = lo; n < hi; n++) s += cnt[n] + 1;
  sums[t] = s;
  __syncthreads();
  for (int off = 1; off < 256; off <<= 1) {
    int v = (t >= off) ? sums[t - off] : 0;
    __syncthreads();
    sums[t] += v;
    __syncthreads();
  }
  int run = sums[t] - s;  // exclusive prefix
  for (int n = lo; n < hi; n++) { rowptr[n] = run; run += cnt[n] + 1; }
  if (t == 255) rowptr[N] = run;
}

// ---------------- CSR fill (edges + self loops) ----------------
__global__ void k_fill(const int* __restrict__ dst, const int* __restrict__ rowptr,
                       int* __restrict__ fill, int* __restrict__ eidx, int N, int E) {
  int t = blockIdx.x * 256 + threadIdx.x;
  if (t < E) {
    int d = dst[t];
    int pos = rowptr[d] + atomicAdd(&fill[d], 1);
    eidx[pos] = t;
  } else if (t < E + N) {
    int n = t - E;
    eidx[rowptr[n + 1] - 1] = E + n;  // self loop id
  }
}

// ---------------- loop_ea: per-node mean of incoming edge attrs ----------------
__global__ __launch_bounds__(256) void k_lea(const float* __restrict__ ew,
                                             const int* __restrict__ rowptr,
                                             const int* __restrict__ eidx,
                                             float* __restrict__ lea, int N) {
  int wave = threadIdx.x >> 6, lane = threadIdx.x & 63;
  int node = blockIdx.x * 4 + wave;
  if (node >= N) return;
  int begin = rowptr[node], end = rowptr[node + 1] - 1;  // exclude self-loop slot
  int ch = lane & 31, half = lane >> 5;
  float s = 0.f;
  for (int p = begin + half; p < end; p += 2) {
    int eid = eidx[p];
    s += ew[(size_t)eid * EDIMX + ch];
  }
  s += __shfl_xor(s, 32, 64);
  int deg = end - begin;
  if (lane < 32) lea[(size_t)node * EDIMX + ch] = s / (float)(deg > 0 ? deg : 1);
}

// ---------------- MFMA bf16 GEMM: C[M,N] = A[M,K] @ BT[N,K]^T ----------------
// block = 64x64 tile (4 waves of 32x32); fragments loaded straight from global.
// A-frag: A[m0+(lane&15)][k0+quad*8+j]; B-frag: BT[n0+(lane&15)][k0+quad*8+j];
// C/D: col=lane&15, row=quad*4+reg  [verified layouts, guide §3]
template <bool BIAS, bool RELU, bool OUTBF16>
__global__ __launch_bounds__(256) void k_gemm_mfma(const unsigned short* __restrict__ A,
                                                   const unsigned short* __restrict__ BT,
                                                   const float* __restrict__ bias,
                                                   void* __restrict__ C, int M, int K, int N) {
  int tid = threadIdx.x;
  int wave = tid >> 6, lane = tid & 63;
  int quad = lane >> 4, l16 = lane & 15;
  int m0 = blockIdx.x * 64 + (wave & 1) * 32;
  int n0 = blockIdx.y * 64 + (wave >> 1) * 32;
  int mA0 = m0 + l16;
  if (mA0 > M - 1) mA0 = M - 1;
  int mA1 = m0 + 16 + l16;
  if (mA1 > M - 1) mA1 = M - 1;
  const bfrag* a0p = (const bfrag*)(A + (size_t)mA0 * K + quad * 8);
  const bfrag* a1p = (const bfrag*)(A + (size_t)mA1 * K + quad * 8);
  const bfrag* b0p = (const bfrag*)(BT + (size_t)(n0 + l16) * K + quad * 8);
  const bfrag* b1p = (const bfrag*)(BT + (size_t)(n0 + 16 + l16) * K + quad * 8);
  f32x4 acc00 = {0.f, 0.f, 0.f, 0.f}, acc01 = {0.f, 0.f, 0.f, 0.f};
  f32x4 acc10 = {0.f, 0.f, 0.f, 0.f}, acc11 = {0.f, 0.f, 0.f, 0.f};
  int ksteps = K >> 5;  // 32 k per step; frag pointer step = 32*2B/16B = 4
  for (int kk = 0; kk < ksteps; kk++) {
    bfrag a0 = a0p[kk * 4];
    bfrag a1 = a1p[kk * 4];
    bfrag b0 = b0p[kk * 4];
    bfrag b1 = b1p[kk * 4];
    acc00 = __builtin_amdgcn_mfma_f32_16x16x32_bf16(a0, b0, acc00, 0, 0, 0);
    acc01 = __builtin_amdgcn_mfma_f32_16x16x32_bf16(a0, b1, acc01, 0, 0, 0);
    acc10 = __builtin_amdgcn_mfma_f32_16x16x32_bf16(a1, b0, acc10, 0, 0, 0);
    acc11 = __builtin_amdgcn_mfma_f32_16x16x32_bf16(a1, b1, acc11, 0, 0, 0);
  }
  float bv0 = 0.f, bv1 = 0.f;
  if (BIAS) {
    bv0 = bias[n0 + l16];
    bv1 = bias[n0 + 16 + l16];
  }
  int col0 = n0 + l16, col1 = n0 + 16 + l16;
#pragma unroll
  for (int r = 0; r < 4; r++) {
    int row0 = m0 + quad * 4 + r;
    int row1 = m0 + 16 + quad * 4 + r;
    float v00 = acc00[r] + bv0, v01 = acc01[r] + bv1;
    float v10 = acc10[r] + bv0, v11 = acc11[r] + bv1;
    if (RELU) {
      v00 = fmaxf(v00, 0.f); v01 = fmaxf(v01, 0.f);
      v10 = fmaxf(v10, 0.f); v11 = fmaxf(v11, 0.f);
    }
    if (row0 < M) {
      if (OUTBF16) {
        ((unsigned short*)C)[(size_t)row0 * N + col0] = f2b(v00);
        ((unsigned short*)C)[(size_t)row0 * N + col1] = f2b(v01);
      } else {
        ((float*)C)[(size_t)row0 * N + col0] = v00;
        ((float*)C)[(size_t)row0 * N + col1] = v01;
      }
    }
    if (row1 < M) {
      if (OUTBF16) {
        ((unsigned short*)C)[(size_t)row1 * N + col0] = f2b(v10);
        ((unsigned short*)C)[(size_t)row1 * N + col1] = f2b(v11);
      } else {
        ((float*)C)[(size_t)row1 * N + col0] = v10;
        ((float*)C)[(size_t)row1 * N + col1] = v11;
      }
    }
  }
}

// ---------------- fused GATv2 attention: score + online-softmax + aggregate ----------------
__global__ __launch_bounds__(256) void k_gat_fused(const float* __restrict__ xl,
                                                   const float* __restrict__ xr,
                                                   const float* __restrict__ ew,
                                                   const float* __restrict__ lea,
                                                   const float* __restrict__ We,
                                                   const float* __restrict__ att,
                                                   const float* __restrict__ bias,
                                                   const int* __restrict__ rowptr,
                                                   const int* __restrict__ eidx,
                                                   const int* __restrict__ src,
                                                   float* __restrict__ out, int N, int E) {
  __shared__ float We_s[EDIMX * DIMX];  // 32 KB
  __shared__ float att_s[DIMX];
  int tid = threadIdx.x;
  {
    const float4* Wg = (const float4*)We;
    float4* Ws = (float4*)We_s;
    for (int i = tid; i < EDIMX * DIMX / 4; i += 256) Ws[i] = Wg[i];
    att_s[tid] = att[tid];
  }
  __syncthreads();
  int wave = tid >> 6, lane = tid & 63;
  int node = blockIdx.x * 4 + wave;
  if (node >= N) return;
  int begin = rowptr[node], end = rowptr[node + 1];
  int c0 = lane * 4;
  float4 vr = *(const float4*)(xr + (size_t)node * DIMX + c0);
  float4 a4 = *(const float4*)&att_s[c0];
  const float4* Wrow = (const float4*)We_s;
  float m = -3.4e38f, l = 0.f;
  float4 acc = make_float4(0.f, 0.f, 0.f, 0.f);
  for (int p = begin; p < end; p++) {
    int eid = eidx[p];
    int s;
    const float* earow;
    if (eid < E) {
      s = src[eid];
      earow = ew + (size_t)eid * EDIMX;
    } else {
      s = node;
      earow = lea + (size_t)node * EDIMX;
    }
    float eav = (lane < EDIMX) ? earow[lane] : 0.f;
    float4 vl = *(const float4*)(xl + (size_t)s * DIMX + c0);
    float ee0 = 0.f, ee1 = 0.f, ee2 = 0.f, ee3 = 0.f;
#pragma unroll
    for (int k = 0; k < EDIMX; k++) {
      float a = __shfl(eav, k, 64);
      float4 wv = Wrow[k * 64 + lane];
      ee0 += a * wv.x; ee1 += a * wv.y; ee2 += a * wv.z; ee3 += a * wv.w;
    }
    float z0 = vl.x + vr.x + ee0, z1 = vl.y + vr.y + ee1;
    float z2 = vl.z + vr.z + ee2, z3 = vl.w + vr.w + ee3;
    z0 = z0 > 0.f ? z0 : 0.2f * z0; z1 = z1 > 0.f ? z1 : 0.2f * z1;
    z2 = z2 > 0.f ? z2 : 0.2f * z2; z3 = z3 > 0.f ? z3 : 0.2f * z3;
    float sc = z0 * a4.x + z1 * a4.y + z2 * a4.z + z3 * a4.w;
    sc += __shfl_xor(sc, 1, 64);
    sc += __shfl_xor(sc, 2, 64);
    sc += __shfl_xor(sc, 4, 64);
    float mn = fmaxf(m, sc);
    float scale = __expf(m - mn);
    float wgt = __expf(sc - mn);
    l = l * scale + wgt;
    acc.x = acc.x * scale + wgt * vl.x;
    acc.y = acc.y * scale + wgt * vl.y;
    acc.z = acc.z * scale + wgt * vl.z;
    acc.w = acc.w * scale + wgt * vl.w;
    m = mn;
  }
  float inv = 1.f / l;
  float4 bia = *(const float4*)(bias + c0);
  acc.x = acc.x * inv + bia.x;
  acc.y = acc.y * inv + bia.y;
  acc.z = acc.z * inv + bia.z;
  acc.w = acc.w * inv + bia.w;
  ((float4*)out)[(size_t)node * 64 + lane] = acc;
}

// ---------------- BN stats (sum, sumsq per channel) ----------------
__global__ __launch_bounds__(256) void k_bnstats(const float* __restrict__ x,
                                                 float* __restrict__ sums, int N) {
  int c = threadIdx.x;
  float s = 0.f, sq = 0.f;
  for (int n = blockIdx.x; n < N; n += gridDim.x) {
    float v = x[(size_t)n * DIMX + c];
    s += v; sq += v * v;
  }
  atomicAdd(&sums[c], s);
  atomicAdd(&sums[DIMX + c], sq);
}

// ---------------- BN + leaky_relu(0.01) + residual (+ bf16 shadow) ----------------
template <bool FINAL>
__global__ __launch_bounds__(256) void k_bnapply(const float* __restrict__ x,
                                                 const float* __restrict__ res,
                                                 const float* __restrict__ sums,
                                                 const float* __restrict__ g,
                                                 const float* __restrict__ b,
                                                 void* __restrict__ out,
                                                 unsigned short* __restrict__ outb, int N,
                                                 const int* __restrict__ flag) {
  int i = blockIdx.x * 256 + threadIdx.x;
  if (i >= N * DIMX) return;
  int c = i & (DIMX - 1);
  float invn = 1.f / (float)N;
  float mu = sums[c] * invn;
  float var = sums[DIMX + c] * invn - mu * mu;
  float rstd = rsqrtf(var + 1e-5f);
  float y = (x[i] - mu) * rstd * g[c] + b[c];
  y = y > 0.f ? y : 0.01f * y;
  y += res[i];
  if (FINAL) {
    if (flag[0]) ((float*)out)[i] = y;
    else ((unsigned short*)out)[i] = f2b(y);
  } else {
    ((float*)out)[i] = y;
    outb[i] = f2b(y);
  }
}

extern "C" void kernel_launch(void* const* d_in, const int* in_sizes, int n_in,
                              void* d_out, int out_size, void* d_ws, size_t ws_size,
                              hipStream_t stream) {
  (void)in_sizes; (void)n_in; (void)out_size; (void)ws_size;
  const int* ei = (const int*)d_in[1];
  const int* srcp = ei;
  const int* dstp = ei + NE;

  char* w = (char*)d_ws;
  auto alloc = [&](size_t bytes) {
    char* p = w;
    w += (bytes + 255) & ~(size_t)255;
    return p;
  };
  float* H0 = (float*)alloc((size_t)NN * DIMX * 4);
  float* H1 = (float*)alloc((size_t)NN * DIMX * 4);
  float* G = (float*)alloc((size_t)NN * DIMX * 4);
  float* XL = (float*)alloc((size_t)NN * DIMX * 4);
  float* XR = (float*)alloc((size_t)NN * DIMX * 4);
  float* LEA = (float*)alloc((size_t)NN * EDIMX * 4);
  float* EWF = (float*)alloc((size_t)NE * EDIMX * 4);
  float* PAR = (float*)alloc((size_t)806656 * 4);
  int* CNT = (int*)alloc((size_t)NN * 4);
  int* ROWPTR = (int*)alloc((size_t)(NN + 1) * 4);
  int* FILL = (int*)alloc((size_t)NN * 4);
  int* EIDX = (int*)alloc((size_t)(NE + NN) * 4);
  float* BNS = (float*)alloc(2 * DIMX * 4);
  int* FLAG = (int*)alloc(256);
  unsigned short* H0b = (unsigned short*)alloc((size_t)NN * DIMX * 2);
  unsigned short* H1b = (unsigned short*)alloc((size_t)NN * DIMX * 2);
  unsigned short* FF1b = (unsigned short*)alloc((size_t)NN * DFFX * 2);
  unsigned short* WLT0 = (unsigned short*)alloc((size_t)DIMX * DIMX * 2);
  unsigned short* WRT0 = (unsigned short*)alloc((size_t)DIMX * DIMX * 2);
  unsigned short* WLT1 = (unsigned short*)alloc((size_t)DIMX * DIMX * 2);
  unsigned short* WRT1 = (unsigned short*)alloc((size_t)DIMX * DIMX * 2);
  unsigned short* W1T = (unsigned short*)alloc((size_t)DIMX * DFFX * 2);
  unsigned short* W2T = (unsigned short*)alloc((size_t)DFFX * DIMX * 2);

  // ---- dtype detect + convert everything to f32 (+ bf16 shadows) ----
  k_detect<<<1, 256, 0, stream>>>((const unsigned short*)d_in[0], FLAG);
  k_cvt_dual<<<(NN * DIMX + 255) / 256, 256, 0, stream>>>(d_in[0], H0, H0b, NN * DIMX, FLAG);
  k_cvt<<<(NE * EDIMX + 255) / 256, 256, 0, stream>>>(d_in[2], EWF, NE * EDIMX, FLAG);
  static const int psz[20] = {65536, 65536, 8192, 256, 256,
                              65536, 65536, 8192, 256, 256,
                              256, 256, 256, 256, 256, 256,
                              262144, 1024, 262144, 256};
  float* pp[20];
  {
    CvtArgs ca;
    int off = 0;
    for (int i = 0; i < 20; i++) {
      pp[i] = PAR + off;
      off += psz[i];
      ca.src[i] = d_in[3 + i];
      ca.dst[i] = pp[i];
      ca.n[i] = psz[i];
    }
    k_cvt_multi<<<dim3(262144 / 256, 20), 256, 0, stream>>>(ca, FLAG);
  }
  const float* g_We[2] = {pp[2], pp[7]};
  const float* g_att[2] = {pp[3], pp[8]};
  const float* g_b[2] = {pp[4], pp[9]};
  const float* bn_g[3] = {pp[10], pp[12], pp[14]};
  const float* bn_b[3] = {pp[11], pp[13], pp[15]};
  const float* ff_b1 = pp[17];
  const float* ff_b2 = pp[19];

  // ---- transpose weights to bf16 [N][K] for MFMA B-operand ----
  k_transpose<<<dim3(8, 8), 256, 0, stream>>>(pp[0], WLT0, DIMX, DIMX);
  k_transpose<<<dim3(8, 8), 256, 0, stream>>>(pp[1], WRT0, DIMX, DIMX);
  k_transpose<<<dim3(8, 8), 256, 0, stream>>>(pp[5], WLT1, DIMX, DIMX);
  k_transpose<<<dim3(8, 8), 256, 0, stream>>>(pp[6], WRT1, DIMX, DIMX);
  k_transpose<<<dim3(32, 8), 256, 0, stream>>>(pp[16], W1T, DIMX, DFFX);
  k_transpose<<<dim3(8, 32), 256, 0, stream>>>(pp[18], W2T, DFFX, DIMX);
  const unsigned short* WLT[2] = {WLT0, WLT1};
  const unsigned short* WRT[2] = {WRT0, WRT1};

  // ---- graph structure (shared by both GAT layers) ----
  hipMemsetAsync(CNT, 0, (size_t)NN * 4, stream);
  hipMemsetAsync(FILL, 0, (size_t)NN * 4, stream);
  k_edge_count<<<(NE + 255) / 256, 256, 0, stream>>>(dstp, CNT, NE);
  k_scan<<<1, 256, 0, stream>>>(CNT, ROWPTR, NN);
  k_fill<<<(NE + NN + 255) / 256, 256, 0, stream>>>(dstp, ROWPTR, FILL, EIDX, NN, NE);
  k_lea<<<(NN + 3) / 4, 256, 0, stream>>>(EWF, ROWPTR, EIDX, LEA, NN);

  const int MB = (NN + 63) / 64;  // 313
  auto run_gat = [&](const float* x, const unsigned short* xb, int li, int bi, float* hout,
                     unsigned short* houtb) {
    k_gemm_mfma<false, false, false><<<dim3(MB, 4), 256, 0, stream>>>(xb, WLT[li], nullptr, XL,
                                                                      NN, DIMX, DIMX);
    k_gemm_mfma<false, false, false><<<dim3(MB, 4), 256, 0, stream>>>(xb, WRT[li], nullptr, XR,
                                                                      NN, DIMX, DIMX);
    k_gat_fused<<<(NN + 3) / 4, 256, 0, stream>>>(XL, XR, EWF, LEA, g_We[li], g_att[li],
                                                  g_b[li], ROWPTR, EIDX, srcp, G, NN, NE);
    hipMemsetAsync(BNS, 0, 2 * DIMX * 4, stream);
    k_bnstats<<<128, 256, 0, stream>>>(G, BNS, NN);
    k_bnapply<false><<<(NN * DIMX + 255) / 256, 256, 0, stream>>>(G, x, BNS, bn_g[bi], bn_b[bi],
                                                                  hout, houtb, NN, FLAG);
  };

  run_gat(H0, H0b, 0, 0, H1, H1b);  // h1 = nf + lrelu(bn(gat1(nf)))
  run_gat(H1, H1b, 1, 1, H0, H0b);  // h2 = h1 + lrelu(bn(gat2(h1)))

  // ---- feed-forward (ff1 emits bf16 directly for ff2) ----
  k_gemm_mfma<true, true, true><<<dim3(MB, DFFX / 64), 256, 0, stream>>>(H0b, W1T, ff_b1, FF1b,
                                                                         NN, DIMX, DFFX);
  k_gemm_mfma<true, false, false><<<dim3(MB, 4), 256, 0, stream>>>(FF1b, W2T, ff_b2, G, NN,
                                                                   DFFX, DIMX);
  hipMemsetAsync(BNS, 0, 2 * DIMX * 4, stream);
  k_bnstats<<<128, 256, 0, stream>>>(G, BNS, NN);
  k_bnapply<true><<<(NN * DIMX + 255) / 256, 256, 0, stream>>>(G, H0, BNS, bn_g[2], bn_b[2],
                                                               d_out, nullptr, NN, FLAG);
}